// Round 1
// baseline (126.886 us; speedup 1.0000x reference)
//
#include <hip/hip_runtime.h>
#include <stdint.h>

// Problem: LTCCell  B=256, I=512, H=512. ALL tensors float32, output float32.
// R3: accum 68us, VGPR=36, occ 20%, VALUBusy 35% -> latency-bound.
// R4: TB=8 + r[8] ILP + 4 waves/SIMD -> accum 48us, VALUBusy 58%, occ 29%.
// R5: side folded into split index -> 2048 blocks (exact machine fit),
//     accum 45us, VALUBusy 61%, busy 27.5us.
// R6 THEORY: busy 27.5us == trans-pipe demand 27.3us (2 trans/elem @16cyc
//     per wave64). Kernel is transcendental-throughput-bound, not memory
//     (10.5% HBM) nor occupancy (exact fit). Fix: share one v_rcp across
//     4 batches via product trick: 1/d_i = (prod_{j!=i} d_j) * rcp(prod d_j).
//     Trans/elem 2 -> 1.25 (floor 27.3 -> 17.1us). Clamp t<=30 so the
//     4-way product <= 2^124 stays finite (sigma error <= 2^-30).
constexpr int NB = 256;
constexpr int NI = 512;
constexpr int NH = 512;

constexpr int TB    = 8;    // batches register-blocked per lane
constexpr int NT    = 32;   // batch tiles: 256/8
constexpr int CHUNK = 32;   // reduction rows per block
constexpr int NSPL  = 32;   // splits: 16 sensory chunks + 16 inter chunks
constexpr int HBLK  = 256;  // h columns per block (== blockDim.x)

__device__ __forceinline__ float fast_exp2(float x) {
#if __has_builtin(__builtin_amdgcn_exp2f)
    return __builtin_amdgcn_exp2f(x);
#else
    return exp2f(x);
#endif
}
__device__ __forceinline__ float fast_rcp(float x) {
#if __has_builtin(__builtin_amdgcn_rcpf)
    return __builtin_amdgcn_rcpf(x);
#else
    return 1.0f / x;
#endif
}

// Each block = (split sigma, batch tile, h half). 2048 blocks x 256 thr =
// 8 blocks/CU = 8 waves/SIMD (exact machine fit). Lane <-> h column, 8
// batches register-blocked per lane. Partials combined via f32 atomics.
__global__ __launch_bounds__(256, 8) void ltc_accum(
    const float* __restrict__ inputs,   // NB x NI
    const float* __restrict__ state,    // NB x NH
    const float* __restrict__ smu, const float* __restrict__ ssg,
    const float* __restrict__ sW,  const float* __restrict__ ser,
    const float* __restrict__ imu, const float* __restrict__ isg,
    const float* __restrict__ iW,  const float* __restrict__ ier,
    float* __restrict__ wsNum, float* __restrict__ wsDen)
{
    __shared__ float xs[CHUNK][TB];   // x/state chunk, [row][batch]

    const int bi    = blockIdx.x;
    const int sigma = bi & (NSPL - 1);          // 32 splits
    const int btile = (bi >> 5) & (NT - 1);     // 32 batch tiles
    const int hhalf = bi >> 10;                 // 2 h halves
    const int b0 = btile * TB;
    const int h  = hhalf * HBLK + threadIdx.x;

    const bool sens = sigma < 16;
    const int  r0   = (sens ? sigma : sigma - 16) * CHUNK;

    // Side-selected pointers (block-uniform -> scalar select, no divergence).
    const float* __restrict__ src  = sens ? inputs : state;   // NB x 512
    const float* __restrict__ Pmu  = sens ? smu : imu;
    const float* __restrict__ Psg  = sens ? ssg : isg;
    const float* __restrict__ PW   = sens ? sW  : iW;
    const float* __restrict__ Per  = sens ? ser : ier;

    // Stage x/state chunk to LDS, [row][batch] layout. CHUNK*TB == 256.
    {
        const int ii = threadIdx.x >> 3, bb = threadIdx.x & (TB - 1);
        xs[ii][bb] = src[(b0 + bb) * 512 + r0 + ii];
    }
    __syncthreads();

    float num[TB], den[TB];
#pragma unroll
    for (int bb = 0; bb < TB; ++bb) { num[bb] = 0.f; den[bb] = 0.f; }

    const float LOG2E = 1.44269504088896340736f;

    // sigmoid((x-mu)*sig) = 1/(1+exp2(c - x*a)), a = sig*log2e, c = mu*a.
    // One v_rcp shared across a group of 4 batches (product trick).
#pragma unroll 2
    for (int ii = 0; ii < CHUNK; ++ii) {
        const int p = (r0 + ii) * NH + h;          // coalesced across lanes
        const float mu = Pmu[p];
        const float a  = Psg[p] * LOG2E;
        const float W  = PW[p];
        const float We = W * Per[p];
        const float c  = mu * a;
#pragma unroll
        for (int g = 0; g < TB; g += 4) {
            // d_i = 1 + exp2(clamp(t_i)).  Clamp keeps d0*d1*d2*d3 < 2^124.
            float d0, d1, d2, d3;
            {
                float t0 = fminf(c - xs[ii][g + 0] * a, 30.0f);
                float t1 = fminf(c - xs[ii][g + 1] * a, 30.0f);
                float t2 = fminf(c - xs[ii][g + 2] * a, 30.0f);
                float t3 = fminf(c - xs[ii][g + 3] * a, 30.0f);
                d0 = 1.0f + fast_exp2(t0);
                d1 = 1.0f + fast_exp2(t1);
                d2 = 1.0f + fast_exp2(t2);
                d3 = 1.0f + fast_exp2(t3);
            }
            const float p01 = d0 * d1;
            const float p23 = d2 * d3;
            const float rD  = fast_rcp(p01 * p23);   // 1 rcp for 4 sigmoids
            const float q01 = p23 * rD;              // = 1/(d0*d1)
            const float q23 = p01 * rD;              // = 1/(d2*d3)
            const float r0v = d1 * q01;              // = 1/d0
            const float r1v = d0 * q01;
            const float r2v = d3 * q23;
            const float r3v = d2 * q23;
            den[g + 0] += W * r0v;  num[g + 0] += We * r0v;
            den[g + 1] += W * r1v;  num[g + 1] += We * r1v;
            den[g + 2] += W * r2v;  num[g + 2] += We * r2v;
            den[g + 3] += W * r3v;  num[g + 3] += We * r3v;
        }
    }

#pragma unroll
    for (int bb = 0; bb < TB; ++bb) {
        unsafeAtomicAdd(&wsNum[(b0 + bb) * NH + h], num[bb]);  // global_atomic_add_f32
        unsafeAtomicAdd(&wsDen[(b0 + bb) * NH + h], den[bb]);
    }
}

// Epilogue: one thread per (b,h). Cheap relative to accumulation.
__global__ __launch_bounds__(256) void ltc_epilogue(
    const float* __restrict__ state,
    const float* __restrict__ vleak, const float* __restrict__ gleak,
    const float* __restrict__ cm,
    const float* __restrict__ wsNum, const float* __restrict__ wsDen,
    float* __restrict__ out)
{
    const int t = blockIdx.x * 256 + threadIdx.x;  // < NB*NH
    const int h = t & (NH - 1);
    const float st = state[t];
    const float gl = gleak[h];
    const float vl = vleak[h];
    const float c  = cm[h];
    const float wnum = wsNum[t];
    const float wden = wsDen[t];
    const float eps = 1e-8f;
    const float G = gl + wden;
    const float tau = c / (G + eps);
    const float numerator = c * st + gl * vl + wnum;
    const float denominator = c + G;
    const float v_inf = numerator / (denominator + eps);
    const float next = v_inf + (st - v_inf) * expf(-0.1f / (tau + eps));
    out[t] = tanhf(next);
}

extern "C" void kernel_launch(void* const* d_in, const int* in_sizes, int n_in,
                              void* d_out, int out_size, void* d_ws, size_t ws_size,
                              hipStream_t stream) {
    const float* inputs = (const float*)d_in[0];
    const float* state  = (const float*)d_in[1];
    const float* smu    = (const float*)d_in[2];
    const float* ssg    = (const float*)d_in[3];
    const float* sW     = (const float*)d_in[4];
    const float* ser    = (const float*)d_in[5];
    const float* imu    = (const float*)d_in[6];
    const float* isg    = (const float*)d_in[7];
    const float* iW     = (const float*)d_in[8];
    const float* ier    = (const float*)d_in[9];
    const float* vleak  = (const float*)d_in[10];
    const float* gleak  = (const float*)d_in[11];
    const float* cm     = (const float*)d_in[12];

    float* wsNum = (float*)d_ws;
    float* wsDen = wsNum + NB * NH;

    // ws is re-poisoned (0xAA) before every timed launch -> zero it ourselves.
    hipMemsetAsync(d_ws, 0, 2ull * NB * NH * sizeof(float), stream);

    ltc_accum<<<dim3(NSPL * NT * 2), dim3(256), 0, stream>>>(
        inputs, state, smu, ssg, sW, ser, imu, isg, iW, ier, wsNum, wsDen);
    ltc_epilogue<<<dim3(NB * NH / 256), dim3(256), 0, stream>>>(
        state, vleak, gleak, cm, wsNum, wsDen, (float*)d_out);
}

// Round 2
// 123.973 us; speedup vs baseline: 1.0235x; 1.0235x over previous
//
#include <hip/hip_runtime.h>
#include <stdint.h>

// Problem: LTCCell  B=256, I=512, H=512. ALL tensors float32, output float32.
// R4: TB=8 + r[8] ILP + 4 waves/SIMD -> accum 48us.
// R5: side folded into split index -> 2048 blocks (exact machine fit),
//     accum 45us, VALUBusy 61%, busy 27.5us.
// R6 FAILED: rcp-sharing (product trick) regressed 45->50us, VALUBusy UP.
//     Falsifies T=16cy trans. Fit from R5+R6: trans ~12cy issue, plain 2cy.
//     R5's busy 27.5us == its issue-slot floor (264cy/ii/wave). The 39%
//     no-issue gap (45 vs 27.5) = all-8-waves vmcnt convoy on the 4 per-ii
//     param loads (compiler only schedules ~1 iter ahead at unroll 2).
// R7: revert to R5 math + explicit DISTANCE-2 register prefetch of the 4
//     param rows (~500 issue-cycles of slack, covers L2 latency). VGPR
//     28->~44 (<=64, occupancy unchanged). Predict accum 45->33-37us,
//     VALUBusy -> 75-85%. If neutral: stalls are not vmcnt -> trans-pipe
//     arbitration is next suspect.
constexpr int NB = 256;
constexpr int NI = 512;
constexpr int NH = 512;

constexpr int TB    = 8;    // batches register-blocked per lane
constexpr int NT    = 32;   // batch tiles: 256/8
constexpr int CHUNK = 32;   // reduction rows per block
constexpr int NSPL  = 32;   // splits: 16 sensory chunks + 16 inter chunks
constexpr int HBLK  = 256;  // h columns per block (== blockDim.x)

__device__ __forceinline__ float fast_exp2(float x) {
#if __has_builtin(__builtin_amdgcn_exp2f)
    return __builtin_amdgcn_exp2f(x);
#else
    return exp2f(x);
#endif
}
__device__ __forceinline__ float fast_rcp(float x) {
#if __has_builtin(__builtin_amdgcn_rcpf)
    return __builtin_amdgcn_rcpf(x);
#else
    return 1.0f / x;
#endif
}

// Each block = (split sigma, batch tile, h half). 2048 blocks x 256 thr =
// 8 blocks/CU = 8 waves/SIMD (exact machine fit). Lane <-> h column, 8
// batches register-blocked per lane. Partials combined via f32 atomics.
__global__ __launch_bounds__(256, 8) void ltc_accum(
    const float* __restrict__ inputs,   // NB x NI
    const float* __restrict__ state,    // NB x NH
    const float* __restrict__ smu, const float* __restrict__ ssg,
    const float* __restrict__ sW,  const float* __restrict__ ser,
    const float* __restrict__ imu, const float* __restrict__ isg,
    const float* __restrict__ iW,  const float* __restrict__ ier,
    float* __restrict__ wsNum, float* __restrict__ wsDen)
{
    __shared__ float xs[CHUNK][TB];   // x/state chunk, [row][batch]

    const int bi    = blockIdx.x;
    const int sigma = bi & (NSPL - 1);          // 32 splits
    const int btile = (bi >> 5) & (NT - 1);     // 32 batch tiles
    const int hhalf = bi >> 10;                 // 2 h halves
    const int b0 = btile * TB;
    const int h  = hhalf * HBLK + threadIdx.x;

    const bool sens = sigma < 16;
    const int  r0   = (sens ? sigma : sigma - 16) * CHUNK;

    // Side-selected pointers (block-uniform -> scalar select, no divergence).
    const float* __restrict__ src  = sens ? inputs : state;   // NB x 512
    const float* __restrict__ Pmu  = sens ? smu : imu;
    const float* __restrict__ Psg  = sens ? ssg : isg;
    const float* __restrict__ PW   = sens ? sW  : iW;
    const float* __restrict__ Per  = sens ? ser : ier;

    // Stage x/state chunk to LDS, [row][batch] layout. CHUNK*TB == 256.
    {
        const int ii = threadIdx.x >> 3, bb = threadIdx.x & (TB - 1);
        xs[ii][bb] = src[(b0 + bb) * 512 + r0 + ii];
    }
    __syncthreads();

    float num[TB], den[TB];
#pragma unroll
    for (int bb = 0; bb < TB; ++bb) { num[bb] = 0.f; den[bb] = 0.f; }

    const float LOG2E = 1.44269504088896340736f;

    // Distance-2 software pipeline on the 4 param streams.
    int p = r0 * NH + h;
    float muA = Pmu[p],      sgA = Psg[p],      WA = PW[p],      erA = Per[p];
    float muB = Pmu[p + NH], sgB = Psg[p + NH], WB = PW[p + NH], erB = Per[p + NH];
    p += 2 * NH;

    // sigmoid((x-mu)*sig) = 1/(1+exp2(c - x*a)), a = sig*log2e, c = mu*a.
    // exp2 overflow -> inf -> rcp gives 0: correct saturation, no clamp.
#pragma unroll 4
    for (int ii = 0; ii < CHUNK; ++ii) {
        const float mu = muA, sg = sgA, W = WA, er = erA;
        // rotate pipeline and issue loads for ii+2 (covered by ~2 iters of issue)
        muA = muB; sgA = sgB; WA = WB; erA = erB;
        if (ii + 2 < CHUNK) {
            muB = Pmu[p]; sgB = Psg[p]; WB = PW[p]; erB = Per[p];
            p += NH;
        }

        const float a  = sg * LOG2E;
        const float We = W * er;
        const float c  = mu * a;
        float r[TB];                               // 8 independent chains
#pragma unroll
        for (int bb = 0; bb < TB; ++bb)
            r[bb] = fast_rcp(1.0f + fast_exp2(c - xs[ii][bb] * a));
#pragma unroll
        for (int bb = 0; bb < TB; ++bb) {
            den[bb] += W  * r[bb];
            num[bb] += We * r[bb];
        }
    }

#pragma unroll
    for (int bb = 0; bb < TB; ++bb) {
        unsafeAtomicAdd(&wsNum[(b0 + bb) * NH + h], num[bb]);  // global_atomic_add_f32
        unsafeAtomicAdd(&wsDen[(b0 + bb) * NH + h], den[bb]);
    }
}

// Epilogue: one thread per (b,h). Cheap relative to accumulation.
__global__ __launch_bounds__(256) void ltc_epilogue(
    const float* __restrict__ state,
    const float* __restrict__ vleak, const float* __restrict__ gleak,
    const float* __restrict__ cm,
    const float* __restrict__ wsNum, const float* __restrict__ wsDen,
    float* __restrict__ out)
{
    const int t = blockIdx.x * 256 + threadIdx.x;  // < NB*NH
    const int h = t & (NH - 1);
    const float st = state[t];
    const float gl = gleak[h];
    const float vl = vleak[h];
    const float c  = cm[h];
    const float wnum = wsNum[t];
    const float wden = wsDen[t];
    const float eps = 1e-8f;
    const float G = gl + wden;
    const float tau = c / (G + eps);
    const float numerator = c * st + gl * vl + wnum;
    const float denominator = c + G;
    const float v_inf = numerator / (denominator + eps);
    const float next = v_inf + (st - v_inf) * expf(-0.1f / (tau + eps));
    out[t] = tanhf(next);
}

extern "C" void kernel_launch(void* const* d_in, const int* in_sizes, int n_in,
                              void* d_out, int out_size, void* d_ws, size_t ws_size,
                              hipStream_t stream) {
    const float* inputs = (const float*)d_in[0];
    const float* state  = (const float*)d_in[1];
    const float* smu    = (const float*)d_in[2];
    const float* ssg    = (const float*)d_in[3];
    const float* sW     = (const float*)d_in[4];
    const float* ser    = (const float*)d_in[5];
    const float* imu    = (const float*)d_in[6];
    const float* isg    = (const float*)d_in[7];
    const float* iW     = (const float*)d_in[8];
    const float* ier    = (const float*)d_in[9];
    const float* vleak  = (const float*)d_in[10];
    const float* gleak  = (const float*)d_in[11];
    const float* cm     = (const float*)d_in[12];

    float* wsNum = (float*)d_ws;
    float* wsDen = wsNum + NB * NH;

    // ws is re-poisoned (0xAA) before every timed launch -> zero it ourselves.
    hipMemsetAsync(d_ws, 0, 2ull * NB * NH * sizeof(float), stream);

    ltc_accum<<<dim3(NSPL * NT * 2), dim3(256), 0, stream>>>(
        inputs, state, smu, ssg, sW, ser, imu, isg, iW, ier, wsNum, wsDen);
    ltc_epilogue<<<dim3(NB * NH / 256), dim3(256), 0, stream>>>(
        state, vleak, gleak, cm, wsNum, wsDen, (float*)d_out);
}

// Round 3
// 123.334 us; speedup vs baseline: 1.0288x; 1.0052x over previous
//
#include <hip/hip_runtime.h>
#include <stdint.h>

// Problem: LTCCell  B=256, I=512, H=512. ALL tensors float32, output float32.
// R5 (best inner loop): 2048 blocks, TB=8, 8 waves/SIMD, accum 45us,
//     VALUBusy 61%. R6 (rcp-sharing) FAILED 50us: chain-depth killed ILP.
// R7 (dist-2 prefetch) NEUTRAL 46us, FETCH doubled: compiler load batching
//     broken, vmcnt-convoy theory falsified. Inner loop reverted to R5.
// R8 THEORY: accum is sticky at ~45us across 3 different inner loops ->
//     attack the OTHER 79us: 3 serialized launches + 2MB memset.
//     Store partials (float2, raceless per-sigma slices) instead of
//     atomics -> memset launch disappears, 3 launches -> 2. Epilogue sums
//     32 slices (33.5MB read, ~8us). ws_size >= 32MiB required; host-side
//     fallback to the R5 atomic path otherwise (no risk).
constexpr int NB = 256;
constexpr int NI = 512;
constexpr int NH = 512;

constexpr int TB    = 8;    // batches register-blocked per lane
constexpr int NT    = 32;   // batch tiles: 256/8
constexpr int CHUNK = 32;   // reduction rows per block
constexpr int NSPL  = 32;   // splits: 16 sensory chunks + 16 inter chunks
constexpr int HBLK  = 256;  // h columns per block (== blockDim.x)

__device__ __forceinline__ float fast_exp2(float x) {
#if __has_builtin(__builtin_amdgcn_exp2f)
    return __builtin_amdgcn_exp2f(x);
#else
    return exp2f(x);
#endif
}
__device__ __forceinline__ float fast_rcp(float x) {
#if __has_builtin(__builtin_amdgcn_rcpf)
    return __builtin_amdgcn_rcpf(x);
#else
    return 1.0f / x;
#endif
}

// Shared body: computes num[TB], den[TB] for this block's (sigma, btile,
// hhalf) unit. Exact R5 inner loop (measured best: 45.0us).
template <typename FlushFn>
__device__ __forceinline__ void ltc_accum_body(
    const float* __restrict__ inputs, const float* __restrict__ state,
    const float* __restrict__ smu, const float* __restrict__ ssg,
    const float* __restrict__ sW,  const float* __restrict__ ser,
    const float* __restrict__ imu, const float* __restrict__ isg,
    const float* __restrict__ iW,  const float* __restrict__ ier,
    FlushFn flush)
{
    __shared__ float xs[CHUNK][TB];   // x/state chunk, [row][batch]

    const int bi    = blockIdx.x;
    const int sigma = bi & (NSPL - 1);          // 32 splits
    const int btile = (bi >> 5) & (NT - 1);     // 32 batch tiles
    const int hhalf = bi >> 10;                 // 2 h halves
    const int b0 = btile * TB;
    const int h  = hhalf * HBLK + threadIdx.x;

    const bool sens = sigma < 16;
    const int  r0   = (sens ? sigma : sigma - 16) * CHUNK;

    // Side-selected pointers (block-uniform -> scalar select, no divergence).
    const float* __restrict__ src  = sens ? inputs : state;   // NB x 512
    const float* __restrict__ Pmu  = sens ? smu : imu;
    const float* __restrict__ Psg  = sens ? ssg : isg;
    const float* __restrict__ PW   = sens ? sW  : iW;
    const float* __restrict__ Per  = sens ? ser : ier;

    // Stage x/state chunk to LDS, [row][batch] layout. CHUNK*TB == 256.
    {
        const int ii = threadIdx.x >> 3, bb = threadIdx.x & (TB - 1);
        xs[ii][bb] = src[(b0 + bb) * 512 + r0 + ii];
    }
    __syncthreads();

    float num[TB], den[TB];
#pragma unroll
    for (int bb = 0; bb < TB; ++bb) { num[bb] = 0.f; den[bb] = 0.f; }

    const float LOG2E = 1.44269504088896340736f;

    // sigmoid((x-mu)*sig) = 1/(1+exp2(c - x*a)), a = sig*log2e, c = mu*a.
    // exp2 overflow -> inf -> rcp gives 0: correct saturation.
#pragma unroll 2
    for (int ii = 0; ii < CHUNK; ++ii) {
        const int p = (r0 + ii) * NH + h;          // coalesced across lanes
        const float mu = Pmu[p];
        const float a  = Psg[p] * LOG2E;
        const float W  = PW[p];
        const float We = W * Per[p];
        const float c  = mu * a;
        float r[TB];                               // 8 independent chains
#pragma unroll
        for (int bb = 0; bb < TB; ++bb)
            r[bb] = fast_rcp(1.0f + fast_exp2(c - xs[ii][bb] * a));
#pragma unroll
        for (int bb = 0; bb < TB; ++bb) {
            den[bb] += W  * r[bb];
            num[bb] += We * r[bb];
        }
    }

    flush(sigma, b0, h, num, den);
}

// ---------------- Path A: partial-store (needs ws >= 32 MiB) --------------
// ws layout: float2 wp[NSPL][NB][NH], wp[s][b][h] = {num, den} partial.
__global__ __launch_bounds__(256, 8) void ltc_accum_ps(
    const float* __restrict__ inputs, const float* __restrict__ state,
    const float* __restrict__ smu, const float* __restrict__ ssg,
    const float* __restrict__ sW,  const float* __restrict__ ser,
    const float* __restrict__ imu, const float* __restrict__ isg,
    const float* __restrict__ iW,  const float* __restrict__ ier,
    float2* __restrict__ wp)
{
    ltc_accum_body(inputs, state, smu, ssg, sW, ser, imu, isg, iW, ier,
        [&](int sigma, int b0, int h, const float* num, const float* den) {
#pragma unroll
            for (int bb = 0; bb < TB; ++bb)
                wp[((size_t)sigma * NB + (b0 + bb)) * NH + h] =
                    make_float2(num[bb], den[bb]);
        });
}

__global__ __launch_bounds__(256) void ltc_epilogue_ps(
    const float* __restrict__ state,
    const float* __restrict__ vleak, const float* __restrict__ gleak,
    const float* __restrict__ cm,
    const float2* __restrict__ wp,
    float* __restrict__ out)
{
    const int t = blockIdx.x * 256 + threadIdx.x;  // < NB*NH, t = b*NH+h
    const int h = t & (NH - 1);
    float wnum = 0.f, wden = 0.f;
#pragma unroll
    for (int s = 0; s < NSPL; ++s) {
        const float2 v = wp[(size_t)s * NB * NH + t];   // coalesced dwordx2
        wnum += v.x; wden += v.y;
    }
    const float st = state[t];
    const float gl = gleak[h];
    const float vl = vleak[h];
    const float c  = cm[h];
    const float eps = 1e-8f;
    const float G = gl + wden;
    const float tau = c / (G + eps);
    const float numerator = c * st + gl * vl + wnum;
    const float denominator = c + G;
    const float v_inf = numerator / (denominator + eps);
    const float next = v_inf + (st - v_inf) * expf(-0.1f / (tau + eps));
    out[t] = tanhf(next);
}

// ---------------- Path B: fallback, exact R5 (atomics + memset) -----------
__global__ __launch_bounds__(256, 8) void ltc_accum(
    const float* __restrict__ inputs, const float* __restrict__ state,
    const float* __restrict__ smu, const float* __restrict__ ssg,
    const float* __restrict__ sW,  const float* __restrict__ ser,
    const float* __restrict__ imu, const float* __restrict__ isg,
    const float* __restrict__ iW,  const float* __restrict__ ier,
    float* __restrict__ wsNum, float* __restrict__ wsDen)
{
    ltc_accum_body(inputs, state, smu, ssg, sW, ser, imu, isg, iW, ier,
        [&](int /*sigma*/, int b0, int h, const float* num, const float* den) {
#pragma unroll
            for (int bb = 0; bb < TB; ++bb) {
                unsafeAtomicAdd(&wsNum[(b0 + bb) * NH + h], num[bb]);
                unsafeAtomicAdd(&wsDen[(b0 + bb) * NH + h], den[bb]);
            }
        });
}

__global__ __launch_bounds__(256) void ltc_epilogue(
    const float* __restrict__ state,
    const float* __restrict__ vleak, const float* __restrict__ gleak,
    const float* __restrict__ cm,
    const float* __restrict__ wsNum, const float* __restrict__ wsDen,
    float* __restrict__ out)
{
    const int t = blockIdx.x * 256 + threadIdx.x;  // < NB*NH
    const int h = t & (NH - 1);
    const float st = state[t];
    const float gl = gleak[h];
    const float vl = vleak[h];
    const float c  = cm[h];
    const float wnum = wsNum[t];
    const float wden = wsDen[t];
    const float eps = 1e-8f;
    const float G = gl + wden;
    const float tau = c / (G + eps);
    const float numerator = c * st + gl * vl + wnum;
    const float denominator = c + G;
    const float v_inf = numerator / (denominator + eps);
    const float next = v_inf + (st - v_inf) * expf(-0.1f / (tau + eps));
    out[t] = tanhf(next);
}

extern "C" void kernel_launch(void* const* d_in, const int* in_sizes, int n_in,
                              void* d_out, int out_size, void* d_ws, size_t ws_size,
                              hipStream_t stream) {
    const float* inputs = (const float*)d_in[0];
    const float* state  = (const float*)d_in[1];
    const float* smu    = (const float*)d_in[2];
    const float* ssg    = (const float*)d_in[3];
    const float* sW     = (const float*)d_in[4];
    const float* ser    = (const float*)d_in[5];
    const float* imu    = (const float*)d_in[6];
    const float* isg    = (const float*)d_in[7];
    const float* iW     = (const float*)d_in[8];
    const float* ier    = (const float*)d_in[9];
    const float* vleak  = (const float*)d_in[10];
    const float* gleak  = (const float*)d_in[11];
    const float* cm     = (const float*)d_in[12];

    const size_t PS_WS = (size_t)NSPL * NB * NH * sizeof(float2);  // 32 MiB

    if (ws_size >= PS_WS) {
        // Path A: raceless partial stores -> no memset, 2 launches.
        float2* wp = (float2*)d_ws;
        ltc_accum_ps<<<dim3(NSPL * NT * 2), dim3(256), 0, stream>>>(
            inputs, state, smu, ssg, sW, ser, imu, isg, iW, ier, wp);
        ltc_epilogue_ps<<<dim3(NB * NH / 256), dim3(256), 0, stream>>>(
            state, vleak, gleak, cm, wp, (float*)d_out);
    } else {
        // Path B: R5 atomic path (ws re-poisoned 0xAA -> zero it ourselves).
        float* wsNum = (float*)d_ws;
        float* wsDen = wsNum + NB * NH;
        hipMemsetAsync(d_ws, 0, 2ull * NB * NH * sizeof(float), stream);
        ltc_accum<<<dim3(NSPL * NT * 2), dim3(256), 0, stream>>>(
            inputs, state, smu, ssg, sW, ser, imu, isg, iW, ier, wsNum, wsDen);
        ltc_epilogue<<<dim3(NB * NH / 256), dim3(256), 0, stream>>>(
            state, vleak, gleak, cm, wsNum, wsDen, (float*)d_out);
    }
}